// Round 5
// baseline (370.303 us; speedup 1.0000x reference)
//
#include <hip/hip_runtime.h>

// 2-layer LSTM (B=4096,T=512,D=16,H=50)+FC via single-wave MFMA.
// R11: R10 + (1) stager wave removed -- all 8 waves compute; each wave
// self-loads its x B-frag from global into a 2-deep register ring (x is
// recurrence-independent; cvt_pkrtz at use; kg>=2 lanes are don't-care
// since the A-frag is zero there); (2) tile rebalance {2,2,2,2,2,1,1,1}
// -> per-SIMD {4,3,3,3}; (3) depth-2 MFMA trees (+vector add) to cut
// dependency latency; (4) eo clamps dropped (non-binding; products
// <=2^117). h LDS layout, fragment loaders, cell algebra unchanged.

#define TSTEPS 512
#define DIN 16
#define HID 50
#define BPB 16

typedef _Float16 half8 __attribute__((ext_vector_type(8)));
typedef __fp16 fp16x2 __attribute__((ext_vector_type(2)));
typedef float f32x4 __attribute__((ext_vector_type(4)));
typedef float f32x2 __attribute__((ext_vector_type(2)));

#define MF(A, B, C) __builtin_amdgcn_mfma_f32_16x16x32_f16((A), (B), (C), 0, 0, 0)

// LDS: h double-buffered [2][16][144] per layer. No x staging.
#define HBUF 2304
#define H0_O 0
#define H1_O 4608
#define SH_BYTES 9216

// Barrier WITHOUT vmcnt drain: LDS ordering only (x global loads stay in flight).
#define BAR() asm volatile("s_waitcnt lgkmcnt(0)\ns_barrier" ::: "memory")

#define NL2E  (-1.4426950408889634f)   // -log2(e): scale for gates i,f,o
#define P2L2E (2.8853900817779268f)    // +2*log2(e): scale for gate g

__device__ __forceinline__ unsigned pack2h(float a, float b) {
  union { fp16x2 h; unsigned u; } pk;
  pk.h = __builtin_amdgcn_cvt_pkrtz(a, b);
  return pk.u;
}

// Pair-fused LSTM cell on PRE-SCALED gates, f32x2-packed (two independent
// cells A,B per call). g[0]=-L2E*i g[1]=-L2E*f g[2]=+2L2E*g g[3]=-L2E*o.
// C = 2L2E*c. eo clamp dropped (worst |scaled o| ~28 -> q0*q1 <= 2^117,
// rcp result > 2^-126: no overflow, no denormal). ec clamp kept (c grows).
__device__ __forceinline__ f32x2 cell2p(const f32x4 gA, const f32x4 gB, f32x2& C) {
  f32x2 gi = {gA[0], gB[0]}, gf = {gA[1], gB[1]};
  f32x2 gg = {gA[2], gB[2]}, go = {gA[3], gB[3]};
  f32x2 ei, ef, eg, eo;
  ei[0] = __builtin_amdgcn_exp2f(gi[0]); ei[1] = __builtin_amdgcn_exp2f(gi[1]);
  ef[0] = __builtin_amdgcn_exp2f(gf[0]); ef[1] = __builtin_amdgcn_exp2f(gf[1]);
  eg[0] = __builtin_amdgcn_exp2f(gg[0]); eg[1] = __builtin_amdgcn_exp2f(gg[1]);
  eo[0] = __builtin_amdgcn_exp2f(go[0]); eo[1] = __builtin_amdgcn_exp2f(go[1]);
  const f32x2 one = {1.f, 1.f};
  const f32x2 c2 = {P2L2E, P2L2E};
  f32x2 a = one + ei, f = one + ef, b = one + eg;
  f32x2 ab = a * b;
  f32x2 f2 = ef * c2 + c2;                 // 2L2E * f
  f32x2 t = (eg - one) * f2 + C * ab;
  f32x2 p = f * ab;
  f32x2 rp;
  rp[0] = __builtin_amdgcn_rcpf(p[0]);
  rp[1] = __builtin_amdgcn_rcpf(p[1]);
  C = t * rp;
  f32x2 ec;
  ec[0] = __builtin_amdgcn_exp2f(fminf(C[0], 30.f));
  ec[1] = __builtin_amdgcn_exp2f(fminf(C[1], 30.f));
  f32x2 q = (one + eo) * (one + ec);
  float r2 = __builtin_amdgcn_rcpf(q[0] * q[1]);
  f32x2 h;
  h[0] = (ec[0] - 1.f) * (r2 * q[1]);
  h[1] = (ec[1] - 1.f) * (r2 * q[0]);
  return h;
}

// A-frag (fp16, 16x16x32): lane row g'=16gt+(lane&15)=4u+j, k-pos p=kt*32+(lane>>4)*8+i.
// permk: pos p holds source k = 8*(p>>3) + 4*(p&1) + ((p>>1)&3).
// scale: per-row gate scale (j = lane&3), folded into the fp16 fragment.
__device__ __forceinline__ half8 load_wfrag(const float* __restrict__ W, int kld,
                                            bool permk, int kreal, int gt, int kt,
                                            int lane, float scale) {
  const int gp = 16 * gt + (lane & 15);
  const int u = gp >> 2, j = gp & 3;
  const int kb = kt * 32 + (lane >> 4) * 8;
  half8 f;
#pragma unroll
  for (int i = 0; i < 8; ++i) {
    const int p = kb + i;
    const int kk = permk ? ((p & ~7) + (((p & 1) << 2) | ((p >> 1) & 3))) : p;
    float v = (u < HID && kk < kreal) ? W[(j * HID + u) * kld + kk] : 0.f;
    f[i] = (_Float16)(v * scale);
  }
  return f;
}

// load x[tl] fragment halves into two float4 regs (per-lane row bcol, half kg&1)
#define LOADX(R0, R1, TT)                                                      \
  do {                                                                         \
    int tl_ = (TT);                                                            \
    if (tl_ > TSTEPS - 1) tl_ = TSTEPS - 1;                                    \
    const float* p_ = xcol + (size_t)tl_ * DIN;                                \
    (R0) = *(const float4*)p_;                                                 \
    (R1) = *(const float4*)(p_ + 4);                                           \
  } while (0)

// build fp16 B-frag from the two float4s (RTZ pack; kg>=2 lanes don't-care)
#define BXB(BX, R0, R1)                                                        \
  do {                                                                         \
    union { half8 h8; fp16x2 p2[4]; } u_;                                      \
    u_.p2[0] = __builtin_amdgcn_cvt_pkrtz((R0).x, (R0).y);                     \
    u_.p2[1] = __builtin_amdgcn_cvt_pkrtz((R0).z, (R0).w);                     \
    u_.p2[2] = __builtin_amdgcn_cvt_pkrtz((R1).x, (R1).y);                     \
    u_.p2[3] = __builtin_amdgcn_cvt_pkrtz((R1).z, (R1).w);                     \
    (BX) = u_.h8;                                                              \
  } while (0)

extern "C" __global__ void __launch_bounds__(512, 2)
lstm2_v11(const float* __restrict__ x,
          const float* __restrict__ Wih0, const float* __restrict__ Whh0,
          const float* __restrict__ bih0, const float* __restrict__ bhh0,
          const float* __restrict__ Wih1, const float* __restrict__ Whh1,
          const float* __restrict__ bih1, const float* __restrict__ bhh1,
          const float* __restrict__ Wfc, const float* __restrict__ bfc,
          float* __restrict__ out) {
  __shared__ __align__(16) char sh[SH_BYTES];
  const int tid = threadIdx.x;
  const int lane = tid & 63;
  const int wv = tid >> 6;
  const int bcol = lane & 15;
  const int kg = lane >> 4;
  const int bbase = blockIdx.x * BPB;

  // tiles: waves 0-4 own gt {2wv,2wv+1}; waves 5,6,7 own gt 10,11,12.
  const int nt = (wv < 5) ? 2 : 1;
  const int gt0 = (wv < 5) ? 2 * wv : (10 + (wv - 5));

  // per-lane x source: row bcol, float-offset (kg&1)*8
  const float* xcol = x + ((size_t)(bbase + bcol)) * TSTEPS * DIN + (kg & 1) * 8;

  for (int i = tid; i < SH_BYTES / 4; i += 512) ((int*)sh)[i] = 0;

  // ---- register-resident PRE-SCALED fp16 weight fragments + scaled f32 bias ----
  const float wsc = ((lane & 3) == 2) ? P2L2E : NL2E;  // A-frag row j = lane&3
  half8 w0x[2], w0h[2][2], w1i[2][2], w1h[2][2];
  f32x4 bias0v[2] = {{0,0,0,0},{0,0,0,0}}, bias1v[2] = {{0,0,0,0},{0,0,0,0}};
#pragma unroll
  for (int gi = 0; gi < 2; ++gi) {
    if (gi < nt) {
      const int gt = gt0 + gi;
      w0x[gi] = load_wfrag(Wih0, DIN, false, DIN, gt, 0, lane, wsc);
#pragma unroll
      for (int kt = 0; kt < 2; ++kt) {
        w0h[gi][kt] = load_wfrag(Whh0, HID, true, HID, gt, kt, lane, wsc);
        w1i[gi][kt] = load_wfrag(Wih1, HID, true, HID, gt, kt, lane, wsc);
        w1h[gi][kt] = load_wfrag(Whh1, HID, true, HID, gt, kt, lane, wsc);
      }
      const int u = 4 * gt + kg;
      if (u < HID) {
#pragma unroll
        for (int j = 0; j < 4; ++j) {
          const float bs = (j == 2) ? P2L2E : NL2E;
          bias0v[gi][j] = bs * (bih0[j * HID + u] + bhh0[j * HID + u]);
          bias1v[gi][j] = bs * (bih1[j * HID + u] + bhh1[j * HID + u]);
        }
      }
    }
  }

  // Cell-state pairs. NT2: C0={c0_gi0,c0_gi1}, C1={c1_gi0,c1_gi1}.
  // NT1: C0={c1,c0} (layer-paired), C1 unused.
  f32x2 C0 = {0.f, 0.f}, C1 = {0.f, 0.f};
  const int hoff = bcol * 144 + kg * 16;
  // h write byte-offset within an h-buffer (u = 4gt+kg at permuted half pos
  // p(u) = (u&~7) + 2*(u&3) + ((u>>2)&1) = 8*(gt>>1) + 2*kg + (gt&1)).
  const int wo = (nt == 2) ? (bcol * 144 + (gt0 >> 1) * 16 + kg * 4)
                           : (bcol * 144 + (8 * (gt0 >> 1) + 2 * kg + (gt0 & 1)) * 2);

  BAR();  // LDS zeroed

  // ---- prologue: h0[0] = cell(bias0 + Wih0 x[0]) -> h0 buf 0 ----
  float4 a0, a1, b0, b1;
  LOADX(a0, a1, 0);
  half8 bx0;
  BXB(bx0, a0, a1);
  LOADX(a0, a1, 1);  // ring: x[1] for phase 0
  LOADX(b0, b1, 2);  // ring: x[2] for phase 1
  {
    f32x4 r0 = MF(w0x[0], bx0, bias0v[0]);
    if (nt == 2) {
      f32x4 r1 = MF(w0x[1], bx0, bias0v[1]);
      f32x2 H = cell2p(r0, r1, C0);
      *(unsigned*)(sh + H0_O + wo) = pack2h(H[0], H[1]);
    } else {
      f32x2 Cp = {0.f, 0.f};
      f32x2 H = cell2p(r0, r0, Cp);
      *(_Float16*)(sh + H0_O + wo) = (_Float16)H[0];
      C0[0] = 0.f;      // c1 init
      C0[1] = Cp[0];    // c0 from prologue
    }
  }
  BAR();

// NT2 step at parity P (reads h bufs P, writes P^1), depth-2 MFMA trees.
#define STEP2(P, BX)                                                           \
  do {                                                                         \
    half8 bh0[2], bh1[2];                                                      \
    _Pragma("unroll") for (int kt = 0; kt < 2; ++kt) {                         \
      bh0[kt] = *(const half8*)(sh + H0_O + (P)*HBUF + hoff + kt * 64);        \
      bh1[kt] = *(const half8*)(sh + H1_O + (P)*HBUF + hoff + kt * 64);        \
    }                                                                          \
    const f32x4 z = {0.f, 0.f, 0.f, 0.f};                                      \
    f32x4 tq0a = MF(w1i[0][0], bh0[0], bias1v[0]);                             \
    tq0a = MF(w1h[0][0], bh1[0], tq0a);                                        \
    f32x4 tq0b = MF(w1i[0][1], bh0[1], z);                                     \
    tq0b = MF(w1h[0][1], bh1[1], tq0b);                                        \
    f32x4 qv0 = tq0a + tq0b;                                                   \
    f32x4 tq1a = MF(w1i[1][0], bh0[0], bias1v[1]);                             \
    tq1a = MF(w1h[1][0], bh1[0], tq1a);                                        \
    f32x4 tq1b = MF(w1i[1][1], bh0[1], z);                                     \
    tq1b = MF(w1h[1][1], bh1[1], tq1b);                                        \
    f32x4 qv1 = tq1a + tq1b;                                                   \
    f32x4 tr0a = MF(w0x[0], (BX), bias0v[0]);                                  \
    tr0a = MF(w0h[0][0], bh0[0], tr0a);                                        \
    f32x4 tr0b = MF(w0h[0][1], bh0[1], z);                                     \
    f32x4 rv0 = tr0a + tr0b;                                                   \
    f32x4 tr1a = MF(w0x[1], (BX), bias0v[1]);                                  \
    tr1a = MF(w0h[1][0], bh0[0], tr1a);                                        \
    f32x4 tr1b = MF(w0h[1][1], bh0[1], z);                                     \
    f32x4 rv1 = tr1a + tr1b;                                                   \
    f32x2 H1 = cell2p(qv0, qv1, C1);                                           \
    *(unsigned*)(sh + H1_O + ((P) ^ 1) * HBUF + wo) = pack2h(H1[0], H1[1]);    \
    f32x2 H0 = cell2p(rv0, rv1, C0);                                           \
    *(unsigned*)(sh + H0_O + ((P) ^ 1) * HBUF + wo) = pack2h(H0[0], H0[1]);    \
  } while (0)

// NT1 step at parity P: one gt, layer-paired cell; b16 h writes.
#define STEP1(P, BX)                                                           \
  do {                                                                         \
    half8 bh0[2], bh1[2];                                                      \
    _Pragma("unroll") for (int kt = 0; kt < 2; ++kt) {                         \
      bh0[kt] = *(const half8*)(sh + H0_O + (P)*HBUF + hoff + kt * 64);        \
      bh1[kt] = *(const half8*)(sh + H1_O + (P)*HBUF + hoff + kt * 64);        \
    }                                                                          \
    const f32x4 z = {0.f, 0.f, 0.f, 0.f};                                      \
    f32x4 tqa = MF(w1i[0][0], bh0[0], bias1v[0]);                              \
    tqa = MF(w1h[0][0], bh1[0], tqa);                                          \
    f32x4 tqb = MF(w1i[0][1], bh0[1], z);                                      \
    tqb = MF(w1h[0][1], bh1[1], tqb);                                          \
    f32x4 qv = tqa + tqb;                                                      \
    f32x4 tra = MF(w0x[0], (BX), bias0v[0]);                                   \
    tra = MF(w0h[0][0], bh0[0], tra);                                          \
    f32x4 trb = MF(w0h[0][1], bh0[1], z);                                      \
    f32x4 rv = tra + trb;                                                      \
    f32x2 H = cell2p(qv, rv, C0);                                              \
    *(_Float16*)(sh + H1_O + ((P) ^ 1) * HBUF + wo) = (_Float16)H[0];          \
    *(_Float16*)(sh + H0_O + ((P) ^ 1) * HBUF + wo) = (_Float16)H[1];          \
  } while (0)

  for (int s = 0; s < TSTEPS; s += 2) {
    // phase s (P=0): uses x[s+1] (ring A); reload A <- x[s+3]
    {
      half8 bxA;
      BXB(bxA, a0, a1);
      LOADX(a0, a1, s + 3);
      if (nt == 2) { STEP2(0, bxA); } else { STEP1(0, bxA); }
    }
    BAR();
    // phase s+1 (P=1): uses x[s+2] (ring B); reload B <- x[s+4]
    {
      half8 bxB;
      BXB(bxB, b0, b1);
      LOADX(b0, b1, s + 4);
      if (nt == 2) { STEP2(1, bxB); } else { STEP1(1, bxB); }
    }
    BAR();
  }

  // ---- FC epilogue: h1[511] in buf 0; read through pi-permutation ----
  if (tid < BPB) {
    float acc = bfc[0];
#pragma unroll 10
    for (int u = 0; u < HID; ++u) {
      const int pp = (u & ~7) + 2 * (u & 3) + ((u >> 2) & 1);
      float h = (float)(*(const _Float16*)(sh + H1_O + tid * 144 + pp * 2));
      acc = fmaf(Wfc[u], h, acc);
    }
    out[bbase + tid] = acc;
  }
}

extern "C" void kernel_launch(void* const* d_in, const int* in_sizes, int n_in,
                              void* d_out, int out_size, void* d_ws, size_t ws_size,
                              hipStream_t stream) {
  (void)in_sizes; (void)n_in; (void)d_ws; (void)ws_size; (void)out_size;
  lstm2_v11<<<dim3(4096 / BPB), dim3(512), 0, stream>>>(
      (const float*)d_in[0], (const float*)d_in[1], (const float*)d_in[2],
      (const float*)d_in[3], (const float*)d_in[4], (const float*)d_in[5],
      (const float*)d_in[6], (const float*)d_in[7], (const float*)d_in[8],
      (const float*)d_in[9], (const float*)d_in[10], (float*)d_out);
}

// Round 6
// 348.817 us; speedup vs baseline: 1.0616x; 1.0616x over previous
//
#include <hip/hip_runtime.h>

// 2-layer LSTM (B=4096,T=512,D=16,H=50)+FC via single-wave MFMA.
// R12 = R10 (best: 330.7us) + (A) x-ring b128 read predicated on kg<2
// (A-frag zero for k>=16 -> B don't-care; masked lanes skip LDS beats),
// (B) kt=1 h reads predicated on kg<3 (k-slots 56..63 >= HID -> zero A-frag),
// (C) eo clamps dropped (validated in R11, identical absmax).
// Structure, math, layouts otherwise identical to R10.

#define TSTEPS 512
#define DIN 16
#define HID 50
#define BPB 16

typedef _Float16 half8 __attribute__((ext_vector_type(8)));
typedef _Float16 half4v __attribute__((ext_vector_type(4)));
typedef __fp16 fp16x2 __attribute__((ext_vector_type(2)));
typedef float f32x4 __attribute__((ext_vector_type(4)));
typedef float f32x2 __attribute__((ext_vector_type(2)));

#define MF(A, B, C) __builtin_amdgcn_mfma_f32_16x16x32_f16((A), (B), (C), 0, 0, 0)

// LDS: h double-buffered [2][16][144]; x 4-slot ring [4][16][80].
#define HBUF 2304
#define XBUF 1280
#define H0_O 0
#define H1_O 4608
#define X_O  9216
#define SH_BYTES (9216 + 4 * XBUF)   // 14336

// Barrier WITHOUT vmcnt drain: LDS ordering only (x global loads stay in flight).
#define BAR() asm volatile("s_waitcnt lgkmcnt(0)\ns_barrier" ::: "memory")

#define NL2E  (-1.4426950408889634f)   // -log2(e): scale for gates i,f,o
#define P2L2E (2.8853900817779268f)    // +2*log2(e): scale for gate g

__device__ __forceinline__ unsigned pack2h(float a, float b) {
  union { fp16x2 h; unsigned u; } pk;
  pk.h = __builtin_amdgcn_cvt_pkrtz(a, b);
  return pk.u;
}

// Pair-fused LSTM cell on PRE-SCALED gates, f32x2-packed (two independent
// cells A,B per call). g[0]=-L2E*i g[1]=-L2E*f g[2]=+2L2E*g g[3]=-L2E*o.
// C = 2L2E*c. eo clamp dropped (R11-validated: worst |scaled o| keeps the
// shared pair product < 2^127). ec clamp kept (c accumulates over 512 steps).
__device__ __forceinline__ f32x2 cell2p(const f32x4 gA, const f32x4 gB, f32x2& C) {
  f32x2 gi = {gA[0], gB[0]}, gf = {gA[1], gB[1]};
  f32x2 gg = {gA[2], gB[2]}, go = {gA[3], gB[3]};
  f32x2 ei, ef, eg, eo;
  ei[0] = __builtin_amdgcn_exp2f(gi[0]); ei[1] = __builtin_amdgcn_exp2f(gi[1]);
  ef[0] = __builtin_amdgcn_exp2f(gf[0]); ef[1] = __builtin_amdgcn_exp2f(gf[1]);
  eg[0] = __builtin_amdgcn_exp2f(gg[0]); eg[1] = __builtin_amdgcn_exp2f(gg[1]);
  eo[0] = __builtin_amdgcn_exp2f(go[0]); eo[1] = __builtin_amdgcn_exp2f(go[1]);
  const f32x2 one = {1.f, 1.f};
  const f32x2 c2 = {P2L2E, P2L2E};
  f32x2 a = one + ei, f = one + ef, b = one + eg;
  f32x2 ab = a * b;
  f32x2 f2 = ef * c2 + c2;                 // 2L2E * f
  f32x2 t = (eg - one) * f2 + C * ab;
  f32x2 p = f * ab;
  f32x2 rp;
  rp[0] = __builtin_amdgcn_rcpf(p[0]);
  rp[1] = __builtin_amdgcn_rcpf(p[1]);
  C = t * rp;
  f32x2 ec;
  ec[0] = __builtin_amdgcn_exp2f(fminf(C[0], 30.f));
  ec[1] = __builtin_amdgcn_exp2f(fminf(C[1], 30.f));
  f32x2 q = (one + eo) * (one + ec);
  float r2 = __builtin_amdgcn_rcpf(q[0] * q[1]);
  f32x2 h;
  h[0] = (ec[0] - 1.f) * (r2 * q[1]);
  h[1] = (ec[1] - 1.f) * (r2 * q[0]);
  return h;
}

// A-frag (fp16, 16x16x32): lane row g'=16gt+(lane&15)=4u+j, k-pos p=kt*32+(lane>>4)*8+i.
// permk: pos p holds source k = 8*(p>>3) + 4*(p&1) + ((p>>1)&3).
// scale: per-row gate scale (j = lane&3), folded into the fp16 fragment.
__device__ __forceinline__ half8 load_wfrag(const float* __restrict__ W, int kld,
                                            bool permk, int kreal, int gt, int kt,
                                            int lane, float scale) {
  const int gp = 16 * gt + (lane & 15);
  const int u = gp >> 2, j = gp & 3;
  const int kb = kt * 32 + (lane >> 4) * 8;
  half8 f;
#pragma unroll
  for (int i = 0; i < 8; ++i) {
    const int p = kb + i;
    const int kk = permk ? ((p & ~7) + (((p & 1) << 2) | ((p >> 1) & 3))) : p;
    float v = (u < HID && kk < kreal) ? W[(j * HID + u) * kld + kk] : 0.f;
    f[i] = (_Float16)(v * scale);
  }
  return f;
}

extern "C" __global__ void __launch_bounds__(512, 2)
lstm2_v12(const float* __restrict__ x,
          const float* __restrict__ Wih0, const float* __restrict__ Whh0,
          const float* __restrict__ bih0, const float* __restrict__ bhh0,
          const float* __restrict__ Wih1, const float* __restrict__ Whh1,
          const float* __restrict__ bih1, const float* __restrict__ bhh1,
          const float* __restrict__ Wfc, const float* __restrict__ bfc,
          float* __restrict__ out) {
  __shared__ __align__(16) char sh[SH_BYTES];
  const int tid = threadIdx.x;
  const int lane = tid & 63;
  const int wv = tid >> 6;
  const int bcol = lane & 15;
  const int kg = lane >> 4;
  const int bbase = blockIdx.x * BPB;
  const bool comp = (wv < 7);

  // x-staging mapping (wave 7): lane -> (batch row sbb, float-quad q)
  const int sbb = lane >> 2, q = lane & 3;
  const float* xrow = x + ((size_t)(bbase + sbb) * TSTEPS) * DIN + q * 4;

  for (int i = tid; i < SH_BYTES / 4; i += 512) ((int*)sh)[i] = 0;

  // ---- register-resident PRE-SCALED fp16 weight fragments + scaled f32 bias ----
  const float wsc = ((lane & 3) == 2) ? P2L2E : NL2E;  // A-frag row j = lane&3
  half8 w0x[2], w0h[2][2], w1i[2][2], w1h[2][2];
  f32x4 bias0v[2] = {{0,0,0,0},{0,0,0,0}}, bias1v[2] = {{0,0,0,0},{0,0,0,0}};
  if (comp) {
#pragma unroll
    for (int gi = 0; gi < 2; ++gi) {
      const int gt = 2 * wv + gi;
      w0x[gi] = load_wfrag(Wih0, DIN, false, DIN, gt, 0, lane, wsc);
#pragma unroll
      for (int kt = 0; kt < 2; ++kt) {
        w0h[gi][kt] = load_wfrag(Whh0, HID, true, HID, gt, kt, lane, wsc);
        w1i[gi][kt] = load_wfrag(Wih1, HID, true, HID, gt, kt, lane, wsc);
        w1h[gi][kt] = load_wfrag(Whh1, HID, true, HID, gt, kt, lane, wsc);
      }
      const int u = 8 * wv + 4 * gi + kg;
      if (u < HID) {
#pragma unroll
        for (int j = 0; j < 4; ++j) {
          const float bs = (j == 2) ? P2L2E : NL2E;
          bias0v[gi][j] = bs * (bih0[j * HID + u] + bhh0[j * HID + u]);
          bias1v[gi][j] = bs * (bih1[j * HID + u] + bhh1[j * HID + u]);
        }
      }
    }
  }
  f32x2 C0 = {0.f, 0.f}, C1 = {0.f, 0.f};  // scaled cell states, paired over gi
  const int hoff = bcol * 144 + kg * 16;
  const int xoff = bcol * 80 + kg * 16;
  const int wo32 = bcol * 144 + wv * 16 + kg * 4;
  const half8 zh8 = {0, 0, 0, 0, 0, 0, 0, 0};

  BAR();  // LDS zeroed

  // stage x[0..2] -> slots 0..2 (wave 7, direct)
  if (wv == 7) {
#pragma unroll
    for (int t = 0; t < 3; ++t) {
      float4 xq = *(const float4*)(xrow + (size_t)t * DIN);
      half4v h4;
#pragma unroll
      for (int i = 0; i < 4; ++i) h4[i] = (_Float16)((const float*)&xq)[i];
      *(half4v*)(sh + X_O + t * XBUF + sbb * 80 + q * 8) = h4;
    }
  }
  BAR();

  // prologue step: h0[0] = cell(bias0 + Wih0 x[0]) -> h0 buf 0; prefetch x[1] to reg.
  float4 xrA, xrB;
  half8 bxc = zh8;
  if (comp) {
    half8 bx0 = zh8;
    if (kg < 2) {
      bx0 = *(const half8*)(sh + X_O + 0 * XBUF + xoff);
      bxc = *(const half8*)(sh + X_O + 1 * XBUF + xoff);
    }
    f32x4 a0 = MF(w0x[0], bx0, bias0v[0]);
    f32x4 a1 = MF(w0x[1], bx0, bias0v[1]);
    f32x2 H0 = cell2p(a0, a1, C0);
    *(unsigned*)(sh + H0_O + wo32) = pack2h(H0[0], H0[1]);
  } else if (wv == 7) {  // issue the register ring: x[3], x[4]
    xrA = *(const float4*)(xrow + (size_t)3 * DIN);
    xrB = *(const float4*)(xrow + (size_t)4 * DIN);
  }
  BAR();

// one compute step at compile-time h-parity P (reads h bufs P, writes P^1),
// using register x-frag bxc (= x[t+1]), prefetching next phase's x from ring
// slot XSN. MFMA chained into the accumulator; cells layer-paired in f32x2.
// kt=1 h reads predicated on kg<3 (slots 56..63 zero); x read on kg<2.
#define STEPCOMP(P, XSN)                                                       \
  do {                                                                         \
    half8 bh0[2], bh1[2];                                                      \
    bh0[0] = *(const half8*)(sh + H0_O + (P)*HBUF + hoff);                     \
    bh1[0] = *(const half8*)(sh + H1_O + (P)*HBUF + hoff);                     \
    if (kg < 3) {                                                              \
      bh0[1] = *(const half8*)(sh + H0_O + (P)*HBUF + hoff + 64);              \
      bh1[1] = *(const half8*)(sh + H1_O + (P)*HBUF + hoff + 64);              \
    } else {                                                                   \
      bh0[1] = zh8;                                                            \
      bh1[1] = zh8;                                                            \
    }                                                                          \
    half8 bxn = zh8;                                                           \
    if (kg < 2) bxn = *(const half8*)(sh + X_O + (XSN)*XBUF + xoff);           \
    f32x4 rv0 = MF(w0x[0], bxc, bias0v[0]);                                    \
    f32x4 rv1 = MF(w0x[1], bxc, bias0v[1]);                                    \
    rv0 = MF(w0h[0][0], bh0[0], rv0);                                          \
    rv1 = MF(w0h[1][0], bh0[0], rv1);                                          \
    rv0 = MF(w0h[0][1], bh0[1], rv0);                                          \
    rv1 = MF(w0h[1][1], bh0[1], rv1);                                          \
    f32x4 qv0 = MF(w1i[0][0], bh0[0], bias1v[0]);                              \
    f32x4 qv1 = MF(w1i[1][0], bh0[0], bias1v[1]);                              \
    qv0 = MF(w1h[0][0], bh1[0], qv0);                                          \
    qv1 = MF(w1h[1][0], bh1[0], qv1);                                          \
    qv0 = MF(w1i[0][1], bh0[1], qv0);                                          \
    qv1 = MF(w1i[1][1], bh0[1], qv1);                                          \
    qv0 = MF(w1h[0][1], bh1[1], qv0);                                          \
    qv1 = MF(w1h[1][1], bh1[1], qv1);                                          \
    f32x2 H0 = cell2p(rv0, rv1, C0);                                           \
    *(unsigned*)(sh + H0_O + ((P) ^ 1) * HBUF + wo32) = pack2h(H0[0], H0[1]);  \
    f32x2 H1 = cell2p(qv0, qv1, C1);                                           \
    *(unsigned*)(sh + H1_O + ((P) ^ 1) * HBUF + wo32) = pack2h(H1[0], H1[1]);  \
    bxc = bxn;                                                                 \
  } while (0)

// wave 7: ds-write XR (holds x[t+3]) into literal SLOT=(t+3)&3, load x[t+5].
#define STEPX(T, SLOT, XR)                                                     \
  do {                                                                         \
    half4v h4;                                                                 \
    _Pragma("unroll") for (int i = 0; i < 4; ++i)                              \
        h4[i] = (_Float16)((const float*)&(XR))[i];                            \
    *(half4v*)(sh + X_O + (SLOT)*XBUF + sbb * 80 + q * 8) = h4;                \
    int tl = (T) + 5;                                                          \
    if (tl > TSTEPS - 1) tl = TSTEPS - 1;                                      \
    (XR) = *(const float4*)(xrow + (size_t)tl * DIN);                          \
  } while (0)

  for (int s = 0; s < TSTEPS; s += 4) {
    // phase s   (P=0): uses x[s+1] (bxc), prefetch slot 2 = x[s+2]
    if (comp) { STEPCOMP(0, 2); } else if (wv == 7) { STEPX(s, 3, xrA); }
    BAR();
    // phase s+1 (P=1): uses x[s+2], prefetch slot 3 = x[s+3]
    if (comp) { STEPCOMP(1, 3); } else if (wv == 7) { STEPX(s + 1, 0, xrB); }
    BAR();
    // phase s+2 (P=0): uses x[s+3], prefetch slot 0 = x[s+4]
    if (comp) { STEPCOMP(0, 0); } else if (wv == 7) { STEPX(s + 2, 1, xrA); }
    BAR();
    // phase s+3 (P=1): uses x[s+4], prefetch slot 1 = x[s+5]
    if (comp) { STEPCOMP(1, 1); } else if (wv == 7) { STEPX(s + 3, 2, xrB); }
    BAR();
  }

  // ---- FC epilogue: h1[511] in buf 0; read through pi-permutation ----
  if (tid < BPB) {
    float acc = bfc[0];
#pragma unroll 10
    for (int u = 0; u < HID; ++u) {
      const int pp = (u & ~7) + 2 * (u & 3) + ((u >> 2) & 1);
      float h = (float)(*(const _Float16*)(sh + H1_O + tid * 144 + pp * 2));
      acc = fmaf(Wfc[u], h, acc);
    }
    out[bbase + tid] = acc;
  }
}

extern "C" void kernel_launch(void* const* d_in, const int* in_sizes, int n_in,
                              void* d_out, int out_size, void* d_ws, size_t ws_size,
                              hipStream_t stream) {
  (void)in_sizes; (void)n_in; (void)d_ws; (void)ws_size; (void)out_size;
  lstm2_v12<<<dim3(4096 / BPB), dim3(512), 0, stream>>>(
      (const float*)d_in[0], (const float*)d_in[1], (const float*)d_in[2],
      (const float*)d_in[3], (const float*)d_in[4], (const float*)d_in[5],
      (const float*)d_in[6], (const float*)d_in[7], (const float*)d_in[8],
      (const float*)d_in[9], (const float*)d_in[10], (float*)d_out);
}